// Round 2
// baseline (1878.692 us; speedup 1.0000x reference)
//
#include <hip/hip_runtime.h>
#include <hip/hip_bf16.h>
#include <float.h>

#define DD 128
#define NEG_SLOPE 0.2f

__device__ __forceinline__ float lrelu(float v) {
    return fmaxf(v, 0.0f) + NEG_SLOPE * fminf(v, 0.0f);
}

// ---------------- preprocessing ----------------

__global__ void k_hist(const int* __restrict__ dst, int E, int* __restrict__ cnt) {
    int i = blockIdx.x * blockDim.x + threadIdx.x;
    if (i < E) atomicAdd(&cnt[dst[i]], 1);
}

// single-block blocked exclusive scan of (cnt[i]+1), row_ptr[N] = E + N
__global__ __launch_bounds__(1024) void k_scan(const int* __restrict__ cnt,
                                               int* __restrict__ row_ptr, int N) {
    __shared__ int sums[1024];
    int tid = threadIdx.x;
    int total = N + 1;
    int chunk = (total + 1023) / 1024;
    int lo = tid * chunk;
    int hi = min(lo + chunk, total);
    int s = 0;
    for (int i = lo; i < hi; ++i) s += (i < N) ? (cnt[i] + 1) : 0;
    sums[tid] = s;
    __syncthreads();
    for (int off = 1; off < 1024; off <<= 1) {
        int t = (tid >= off) ? sums[tid - off] : 0;
        __syncthreads();
        sums[tid] += t;
        __syncthreads();
    }
    int run = sums[tid] - s;  // exclusive prefix for this thread's chunk
    for (int i = lo; i < hi; ++i) {
        row_ptr[i] = run;
        run += (i < N) ? (cnt[i] + 1) : 0;
    }
}

__global__ void k_scatter(const int* __restrict__ dst, int E, int N,
                          const int* __restrict__ row_ptr, int* __restrict__ fill,
                          const int* __restrict__ cnt, int* __restrict__ eids) {
    int i = blockIdx.x * blockDim.x + threadIdx.x;
    int tot = E + N;
    if (i >= tot) return;
    if (i < E) {
        int d = dst[i];
        int p = atomicAdd(&fill[d], 1);
        eids[row_ptr[d] + p] = i;
    } else {
        int n = i - E;
        eids[row_ptr[n] + cnt[n]] = E + n;  // self-loop in last slot
    }
}

// canonicalize row order: atomic scatter order is launch-dependent; sort each
// row ascending so every call does bitwise-identical work. Self-loop id E+n is
// the row max, so it stays in the last slot.
__global__ void k_sort_rows(const int* __restrict__ row_ptr, int* __restrict__ eids, int N) {
    int n = blockIdx.x * blockDim.x + threadIdx.x;
    if (n >= N) return;
    int s = row_ptr[n], e = row_ptr[n + 1];
    for (int i = s + 1; i < e; ++i) {
        int v = eids[i];
        int j = i - 1;
        while (j >= s && eids[j] > v) { eids[j + 1] = eids[j]; --j; }
        eids[j + 1] = v;
    }
}

// loop_attr[n,:] = mean of incoming edge attrs (0 if none)
__global__ __launch_bounds__(128) void k_loop_attr(const float* __restrict__ ea,
                                                   const int* __restrict__ row_ptr,
                                                   const int* __restrict__ cnt,
                                                   const int* __restrict__ eids,
                                                   float* __restrict__ loop_attr, int N) {
    int n = blockIdx.x;
    int d = threadIdx.x;
    int s = row_ptr[n];
    int c = cnt[n];
    float acc = 0.f;
    for (int p = 0; p < c; ++p) {
        int e = eids[s + p];
        acc += ea[(size_t)e * DD + d];
    }
    loop_attr[(size_t)n * DD + d] = acc / fmaxf((float)c, 1.0f);
}

// ---------------- per-layer kernels ----------------

// Y[N,128] = X[N,128] @ W[128,128] + b[128]   (tile 128x128, 256 thr, 8x8/thread)
__global__ __launch_bounds__(256) void k_gemm_nn(const float* __restrict__ X,
                                                 const float* __restrict__ W,
                                                 const float* __restrict__ b,
                                                 float* __restrict__ Y, int N) {
    __shared__ float As[128][9];   // +1 pad
    __shared__ float Bs[8][128];
    int tid = threadIdx.x;
    int tr = tid >> 4, tc = tid & 15;
    int r0 = blockIdx.x * 128;
    float acc[8][8] = {};
    for (int k0 = 0; k0 < 128; k0 += 8) {
        {   // A tile: 128 rows x 8 k   (256 float4 loads)
            int r = tid >> 1, half = tid & 1;
            int gr = r0 + r;
            float4 v = make_float4(0.f, 0.f, 0.f, 0.f);
            if (gr < N) v = *reinterpret_cast<const float4*>(&X[(size_t)gr * DD + k0 + half * 4]);
            As[r][half * 4 + 0] = v.x;
            As[r][half * 4 + 1] = v.y;
            As[r][half * 4 + 2] = v.z;
            As[r][half * 4 + 3] = v.w;
        }
        {   // B tile: 8 k x 128 cols
            int kk = tid >> 5, c4 = tid & 31;
            *reinterpret_cast<float4*>(&Bs[kk][c4 * 4]) =
                *reinterpret_cast<const float4*>(&W[(size_t)(k0 + kk) * DD + c4 * 4]);
        }
        __syncthreads();
        #pragma unroll
        for (int kk = 0; kk < 8; ++kk) {
            float a[8], bb[8];
            #pragma unroll
            for (int i = 0; i < 8; ++i) a[i] = As[tr * 8 + i][kk];
            #pragma unroll
            for (int j = 0; j < 8; ++j) bb[j] = Bs[kk][tc * 8 + j];
            #pragma unroll
            for (int i = 0; i < 8; ++i)
                #pragma unroll
                for (int j = 0; j < 8; ++j)
                    acc[i][j] += a[i] * bb[j];
        }
        __syncthreads();
    }
    #pragma unroll
    for (int i = 0; i < 8; ++i) {
        int gr = r0 + tr * 8 + i;
        if (gr >= N) continue;
        #pragma unroll
        for (int j0 = 0; j0 < 8; j0 += 4) {
            int c = tc * 8 + j0;
            float4 o;
            o.x = acc[i][j0 + 0] + b[c + 0];
            o.y = acc[i][j0 + 1] + b[c + 1];
            o.z = acc[i][j0 + 2] + b[c + 2];
            o.w = acc[i][j0 + 3] + b[c + 3];
            *reinterpret_cast<float4*>(&Y[(size_t)gr * DD + c]) = o;
        }
    }
}

// fused: ee = ea_row @ We ; t = ee + xl[src] + xr[dst] ; logit = sum(att * lrelu(t))
// tile: 64 edges x 128 cols, 256 threads (8 edge-groups x 32 col-groups of 4)
__global__ __launch_bounds__(256) void k_edge_logits(
    const float* __restrict__ ea, const float* __restrict__ loop_attr,
    const int* __restrict__ srcArr, const int* __restrict__ dstArr,
    const float* __restrict__ We, const float* __restrict__ att,
    const float* __restrict__ xl, const float* __restrict__ xr,
    float* __restrict__ logits, int E, int Etot) {
    __shared__ float As[64][DD];
    __shared__ float Bs[8][DD];
    __shared__ int s_src[64], s_dst[64];
    int tid = threadIdx.x;
    int e0 = blockIdx.x * 64;
    if (tid < 64) {
        int e = e0 + tid;
        int s = 0, d = 0;
        if (e < E) { s = srcArr[e]; d = dstArr[e]; }
        else if (e < Etot) { s = e - E; d = e - E; }
        s_src[tid] = s; s_dst[tid] = d;
    }
    // stage ea tile (self-loop rows come from loop_attr)
    #pragma unroll
    for (int q = 0; q < 8; ++q) {
        int idx = tid + q * 256;          // float4 index
        int r = idx >> 5, c4 = idx & 31;
        int e = e0 + r;
        float4 v = make_float4(0.f, 0.f, 0.f, 0.f);
        if (e < E)         v = *reinterpret_cast<const float4*>(&ea[(size_t)e * DD + c4 * 4]);
        else if (e < Etot) v = *reinterpret_cast<const float4*>(&loop_attr[(size_t)(e - E) * DD + c4 * 4]);
        *reinterpret_cast<float4*>(&As[r][c4 * 4]) = v;
    }
    __syncthreads();
    int tr = tid >> 5, tc = tid & 31;
    int c0 = tc * 4;
    float acc[8][4] = {};
    for (int k0 = 0; k0 < 128; k0 += 8) {
        {   // stage We k-tile
            int kk = tid >> 5, c4 = tid & 31;
            *reinterpret_cast<float4*>(&Bs[kk][c4 * 4]) =
                *reinterpret_cast<const float4*>(&We[(size_t)(k0 + kk) * DD + c4 * 4]);
        }
        __syncthreads();
        #pragma unroll
        for (int kk = 0; kk < 8; ++kk) {
            float4 bv = *reinterpret_cast<float4*>(&Bs[kk][c0]);
            #pragma unroll
            for (int i = 0; i < 8; ++i) {
                float a = As[tr * 8 + i][k0 + kk];
                acc[i][0] += a * bv.x;
                acc[i][1] += a * bv.y;
                acc[i][2] += a * bv.z;
                acc[i][3] += a * bv.w;
            }
        }
        __syncthreads();
    }
    float4 attv = *reinterpret_cast<const float4*>(&att[c0]);
    float part[8];
    #pragma unroll
    for (int i = 0; i < 8; ++i) {
        int r = tr * 8 + i;
        int s = s_src[r], d = s_dst[r];
        float4 xlv = *reinterpret_cast<const float4*>(&xl[(size_t)s * DD + c0]);
        float4 xrv = *reinterpret_cast<const float4*>(&xr[(size_t)d * DD + c0]);
        float t0 = acc[i][0] + xlv.x + xrv.x;
        float t1 = acc[i][1] + xlv.y + xrv.y;
        float t2 = acc[i][2] + xlv.z + xrv.z;
        float t3 = acc[i][3] + xlv.w + xrv.w;
        part[i] = attv.x * lrelu(t0) + attv.y * lrelu(t1) + attv.z * lrelu(t2) + attv.w * lrelu(t3);
    }
    // reduce over the 32 col-group lanes
    #pragma unroll
    for (int i = 0; i < 8; ++i) {
        float p = part[i];
        p += __shfl_xor(p, 16);
        p += __shfl_xor(p, 8);
        p += __shfl_xor(p, 4);
        p += __shfl_xor(p, 2);
        p += __shfl_xor(p, 1);
        part[i] = p;
    }
    if (tc == 0) {
        #pragma unroll
        for (int i = 0; i < 8; ++i) {
            int e = e0 + tr * 8 + i;
            if (e < Etot) logits[e] = part[i];
        }
    }
}

// per-destination softmax + aggregation over CSR; out = segsum(alpha*xl[src]) + bias
__global__ __launch_bounds__(128) void k_node_agg(
    const float* __restrict__ logits, const int* __restrict__ row_ptr,
    const int* __restrict__ eids, const int* __restrict__ srcArr,
    const float* __restrict__ xl, const float* __restrict__ bias,
    float* __restrict__ xout, int N, int E) {
    __shared__ float red[128];
    __shared__ float s_alpha[128];
    __shared__ int s_s[128];
    int n = blockIdx.x;
    int t = threadIdx.x;
    int s = row_ptr[n], e = row_ptr[n + 1];
    // max
    float mx = -FLT_MAX;
    for (int p = s + t; p < e; p += 128) mx = fmaxf(mx, logits[eids[p]]);
    red[t] = mx; __syncthreads();
    for (int off = 64; off; off >>= 1) {
        if (t < off) red[t] = fmaxf(red[t], red[t + off]);
        __syncthreads();
    }
    mx = red[0]; __syncthreads();
    // sum of exp
    float sm = 0.f;
    for (int p = s + t; p < e; p += 128) sm += __expf(logits[eids[p]] - mx);
    red[t] = sm; __syncthreads();
    for (int off = 64; off; off >>= 1) {
        if (t < off) red[t] += red[t + off];
        __syncthreads();
    }
    float inv = 1.0f / red[0];
    float acc = 0.f;
    for (int p0 = s; p0 < e; p0 += 128) {
        int m = min(128, e - p0);
        __syncthreads();
        if (t < m) {
            int eid = eids[p0 + t];
            s_alpha[t] = __expf(logits[eid] - mx) * inv;
            s_s[t] = (eid < E) ? srcArr[eid] : (eid - E);
        }
        __syncthreads();
        for (int q = 0; q < m; ++q)
            acc += s_alpha[q] * xl[(size_t)s_s[q] * DD + t];
    }
    xout[(size_t)n * DD + t] = acc + bias[t];
}

// ---------------- final score + top-k ----------------

__global__ __launch_bounds__(256) void k_scores(const float* __restrict__ X,
                                                const float* __restrict__ Wf,
                                                const float* __restrict__ bf,
                                                float* __restrict__ scores, int N) {
    int gid = blockIdx.x * blockDim.x + threadIdx.x;
    int node = gid >> 6;
    int lane = threadIdx.x & 63;
    if (node >= N) return;
    float2 xv = *reinterpret_cast<const float2*>(&X[(size_t)node * DD + lane * 2]);
    float2 wv = *reinterpret_cast<const float2*>(&Wf[lane * 2]);
    float p = xv.x * wv.x + xv.y * wv.y;
    p += __shfl_xor(p, 32);
    p += __shfl_xor(p, 16);
    p += __shfl_xor(p, 8);
    p += __shfl_xor(p, 4);
    p += __shfl_xor(p, 2);
    p += __shfl_xor(p, 1);
    if (lane == 0) scores[node] = p + bf[0];
}

__device__ __forceinline__ bool tk_better(float a, int ai, float b, int bi) {
    return (a > b) || (a == b && ai < bi);
}

__global__ __launch_bounds__(1024) void k_topk(const float* __restrict__ scores, int N,
                                               float* __restrict__ out) {
    __shared__ float lv[1024 * 10];
    __shared__ int li[1024 * 10];
    int t = threadIdx.x;
    float v[10]; int ix[10];
    #pragma unroll
    for (int j = 0; j < 10; ++j) { v[j] = -FLT_MAX; ix[j] = 0x7fffffff; }
    for (int i = t; i < N; i += 1024) {
        float sv = scores[i];
        if (tk_better(sv, i, v[9], ix[9])) {
            v[9] = sv; ix[9] = i;
            #pragma unroll
            for (int j = 9; j > 0; --j) {
                if (tk_better(v[j], ix[j], v[j - 1], ix[j - 1])) {
                    float tv = v[j]; v[j] = v[j - 1]; v[j - 1] = tv;
                    int ti = ix[j]; ix[j] = ix[j - 1]; ix[j - 1] = ti;
                }
            }
        }
    }
    #pragma unroll
    for (int j = 0; j < 10; ++j) { lv[t * 10 + j] = v[j]; li[t * 10 + j] = ix[j]; }
    __syncthreads();
    for (int sh = 512; sh >= 1; sh >>= 1) {
        if (t < sh) {
            float bv[10]; int bi[10];
            #pragma unroll
            for (int j = 0; j < 10; ++j) { bv[j] = lv[(t + sh) * 10 + j]; bi[j] = li[(t + sh) * 10 + j]; }
            float mv[10]; int mi[10];
            int i1 = 0, i2 = 0;
            #pragma unroll
            for (int k = 0; k < 10; ++k) {
                if (tk_better(v[i1], ix[i1], bv[i2], bi[i2])) { mv[k] = v[i1]; mi[k] = ix[i1]; ++i1; }
                else { mv[k] = bv[i2]; mi[k] = bi[i2]; ++i2; }
            }
            #pragma unroll
            for (int j = 0; j < 10; ++j) {
                v[j] = mv[j]; ix[j] = mi[j];
                lv[t * 10 + j] = v[j]; li[t * 10 + j] = ix[j];
            }
        }
        __syncthreads();
    }
    if (t == 0) {
        #pragma unroll
        for (int j = 0; j < 10; ++j) {
            out[j] = v[j];
            out[10 + j] = (float)ix[j];
        }
    }
}

// ---------------- host launch ----------------

static inline size_t alignup(size_t v) { return (v + 255) & ~(size_t)255; }

extern "C" void kernel_launch(void* const* d_in, const int* in_sizes, int n_in,
                              void* d_out, int out_size, void* d_ws, size_t ws_size,
                              hipStream_t stream) {
    const float* x    = (const float*)d_in[0];
    const int*   ei   = (const int*)d_in[1];
    const float* ea   = (const float*)d_in[2];
    const float* Wl   = (const float*)d_in[3];
    const float* bl   = (const float*)d_in[4];
    const float* Wr   = (const float*)d_in[5];
    const float* br   = (const float*)d_in[6];
    const float* We   = (const float*)d_in[7];
    const float* att  = (const float*)d_in[8];
    const float* bias = (const float*)d_in[9];
    const float* Wf   = (const float*)d_in[10];
    const float* bf   = (const float*)d_in[11];

    int N = in_sizes[0] / DD;
    int E = in_sizes[1] / 2;
    int L = in_sizes[3] / (DD * DD);
    int Etot = E + N;
    const int* src = ei;
    const int* dst = ei + E;

    size_t off = 0;
    char* wsb = (char*)d_ws;
    auto carve = [&](size_t bytes) -> void* { void* p = wsb + off; off += alignup(bytes); return p; };
    int*   cnt       = (int*)carve((size_t)N * 4);
    int*   fill      = (int*)carve((size_t)N * 4);
    int*   row_ptr   = (int*)carve((size_t)(N + 1) * 4);
    int*   eids      = (int*)carve((size_t)Etot * 4);
    float* logits    = (float*)carve((size_t)Etot * 4);
    float* loop_attr = (float*)carve((size_t)N * DD * 4);
    float* xl        = (float*)carve((size_t)N * DD * 4);
    float* xr        = (float*)carve((size_t)N * DD * 4);
    float* xa        = (float*)carve((size_t)N * DD * 4);
    float* xb        = (float*)carve((size_t)N * DD * 4);
    float* scoresBuf = (float*)carve((size_t)N * 4);
    (void)ws_size; (void)n_in; (void)out_size;

    hipMemsetAsync(cnt, 0, (size_t)N * 4, stream);
    hipMemsetAsync(fill, 0, (size_t)N * 4, stream);

    k_hist<<<(E + 255) / 256, 256, 0, stream>>>(dst, E, cnt);
    k_scan<<<1, 1024, 0, stream>>>(cnt, row_ptr, N);
    k_scatter<<<(Etot + 255) / 256, 256, 0, stream>>>(dst, E, N, row_ptr, fill, cnt, eids);
    k_sort_rows<<<(N + 255) / 256, 256, 0, stream>>>(row_ptr, eids, N);
    k_loop_attr<<<N, 128, 0, stream>>>(ea, row_ptr, cnt, eids, loop_attr, N);

    const float* xin = x;
    float* xout = xa;
    int gemmBlocks = (N + 127) / 128;
    int edgeBlocks = (Etot + 63) / 64;
    for (int l = 0; l < L; ++l) {
        k_gemm_nn<<<gemmBlocks, 256, 0, stream>>>(xin, Wl + (size_t)l * DD * DD, bl + (size_t)l * DD, xl, N);
        k_gemm_nn<<<gemmBlocks, 256, 0, stream>>>(xin, Wr + (size_t)l * DD * DD, br + (size_t)l * DD, xr, N);
        k_edge_logits<<<edgeBlocks, 256, 0, stream>>>(ea, loop_attr, src, dst,
                                                      We + (size_t)l * DD * DD, att + (size_t)l * DD,
                                                      xl, xr, logits, E, Etot);
        k_node_agg<<<N, 128, 0, stream>>>(logits, row_ptr, eids, src, xl, bias + (size_t)l * DD, xout, N, E);
        xin = xout;
        xout = (xout == xa) ? xb : xa;
    }
    k_scores<<<(N + 3) / 4, 256, 0, stream>>>(xin, Wf, bf, scoresBuf, N);
    k_topk<<<1, 1024, 0, stream>>>(scoresBuf, N, (float*)d_out);
}